// Round 1
// baseline (362.208 us; speedup 1.0000x reference)
//
#include <hip/hip_runtime.h>
#include <stdint.h>

typedef unsigned short u16;
typedef float v4f __attribute__((ext_vector_type(4)));
typedef short v8s __attribute__((ext_vector_type(8)));

#define B_   8192
#define IN_  1024
#define OUT_ 1024
#define D_   8

#define BM 128
#define BN 128
#define BK 64             // K-tile per barrier pair (32 MFMAs amortize the drain)

__device__ __forceinline__ u16 f2bf(float f) {
  uint32_t u = __float_as_uint(f);
  u += 0x7fffu + ((u >> 16) & 1u);   // round-to-nearest-even (inputs are finite)
  return (u16)(u >> 16);
}

// ---- prep: plain bf16 conversion of input (16 MB) and weights (16 MB) ------
// ~96 MB HBM traffic total; replaces the 128 MB pre-scaled A' (which cost
// ~106 us to build). The w-scale is now applied post-MFMA in registers.
__global__ __launch_bounds__(256) void convert_both(
    const float* __restrict__ input, const float* __restrict__ weights,
    u16* __restrict__ inBf, u16* __restrict__ wtBf) {
  int i4 = blockIdx.x * blockDim.x + threadIdx.x;
  const int n4 = (B_ * IN_) / 4;
  const float* src;
  u16* dst;
  int idx;
  if (i4 < n4) { src = input;   dst = inBf; idx = i4; }
  else         { src = weights; dst = wtBf; idx = i4 - n4; }
  float4 v = ((const float4*)src)[idx];
  ushort4 o;
  o.x = f2bf(v.x); o.y = f2bf(v.y); o.z = f2bf(v.z); o.w = f2bf(v.w);
  ((ushort4*)dst)[idx] = o;
}

__device__ __forceinline__ void gload_lds16(const u16* g, u16* l) {
  typedef __attribute__((address_space(1))) void gvoid;
  typedef __attribute__((address_space(3))) void lvoid;
  __builtin_amdgcn_global_load_lds((gvoid*)g, (lvoid*)l, 16, 0, 0);
}

// ---- main GEMM, per-d accumulation -----------------------------------------
// 512 blocks (exactly 2/CU, no tail), XCD swizzle (id&7 = XCD). BK=64:
// 32 MFMAs per barrier pair. Outer loop over d (8 planes of weights);
// A-tile (bf16 input, unscaled) is re-staged per d but is L2/L3-resident
// (16 MB total), so HBM fetch is ~32 MB instead of A''s 128 MB.
// At each d boundary: fin += w[row,d] * acc (64 VALU FMAs/thread).
// LDS is XOR-swizzled: slot column-chunk j' = j ^ (row&7), applied on the
// GLOBAL side of global_load_lds (LDS dest stays lane-contiguous per the
// wave-uniform-base constraint). Reads de-swizzle: chunk (quad+4h)^(l16&7).
__global__ __launch_bounds__(256) void gemm_perd(
    const u16* __restrict__ A,        // [B_][IN_] bf16 input (unscaled)
    const u16* __restrict__ Wt,       // [D_][OUT_][IN_] bf16
    const float* __restrict__ w,      // [B_][D_]
    const float* __restrict__ biases, // [D_][OUT_]
    float* __restrict__ out) {        // [B_][OUT_]
  __shared__ __align__(16) u16 As[BM * BK];   // 16 KB
  __shared__ __align__(16) u16 Bs[BN * BK];   // 16 KB

  const int id   = blockIdx.x;                // 512 blocks
  const int xcd  = id & 7;
  const int slot = id >> 3;                   // 0..63
  const int by   = xcd + ((slot & 7) << 3);   // 0..63, 8 per XCD
  const int bx   = slot >> 3;                 // 0..7

  const int tid  = threadIdx.x;
  const int wid  = tid >> 6;
  const int lane = tid & 63;
  const int wr   = wid >> 1, wc = wid & 1;
  const int quad = lane >> 4, l16 = lane & 15;
  const int m0   = by * BM;
  const int n0   = bx * BN;

  // ---- staging: 1024 chunks of 16B per 16KB tile; thread -> 4 chunks/matrix
  // chunk c = wid*256 + j*64 + lane  (j=0..3); row = c>>3 = wid*32+j*8+(lane>>3)
  // global col chunk is swizzled: swz = (lane&7) ^ ((lane>>3)&7)  (j-invariant)
  const int swz  = (lane & 7) ^ ((lane >> 3) & 7);
  const int rowS = wid * 32 + (lane >> 3);    // + j*8
  const u16* aBase[4];
  const u16* bBase[4];
  u16* lA[4];
  u16* lB[4];
#pragma unroll
  for (int j = 0; j < 4; ++j) {
    const int row = rowS + j * 8;
    aBase[j] = A  + (size_t)(m0 + row) * IN_ + swz * 8;
    bBase[j] = Wt + (size_t)(n0 + row) * IN_ + swz * 8;
    const int c = wid * 256 + j * 64 + lane;
    lA[j] = As + c * 8;
    lB[j] = Bs + c * 8;
  }

  // ---- fragment LDS offsets (u16 index), de-swizzled
  const int aRow = wr * 64 + l16;
  const int bRow = wc * 64 + l16;
  const int e    = l16 & 7;
  int aC[2], bC[2];
#pragma unroll
  for (int h = 0; h < 2; ++h) {
    aC[h] = ((quad + 4 * h) ^ e) * 8;
    bC[h] = aC[h];
  }

  const v4f vzero = {0.f, 0.f, 0.f, 0.f};
  v4f fin[4][4];
#pragma unroll
  for (int mt = 0; mt < 4; ++mt)
#pragma unroll
    for (int nt = 0; nt < 4; ++nt) fin[mt][nt] = vzero;

  for (int dd = 0; dd < D_; ++dd) {
    const size_t bOffG = (size_t)dd * OUT_ * IN_;     // weights[dd] plane
    v4f acc[4][4];
#pragma unroll
    for (int mt = 0; mt < 4; ++mt)
#pragma unroll
      for (int nt = 0; nt < 4; ++nt) acc[mt][nt] = vzero;

    for (int it = 0; it < IN_ / BK; ++it) {           // 16 iters
      const int i0 = it * BK;
#pragma unroll
      for (int j = 0; j < 4; ++j) gload_lds16(aBase[j] + i0, lA[j]);
#pragma unroll
      for (int j = 0; j < 4; ++j) gload_lds16(bBase[j] + bOffG + i0, lB[j]);
      __builtin_amdgcn_s_waitcnt(0);
      __syncthreads();

#pragma unroll
      for (int h = 0; h < 2; ++h) {
        v8s af[4], bf[4];
#pragma unroll
        for (int mt = 0; mt < 4; ++mt)
          af[mt] = *(const v8s*)(As + (aRow + mt * 16) * BK + aC[h]);
#pragma unroll
        for (int nt = 0; nt < 4; ++nt)
          bf[nt] = *(const v8s*)(Bs + (bRow + nt * 16) * BK + bC[h]);
#pragma unroll
        for (int mt = 0; mt < 4; ++mt)
#pragma unroll
          for (int nt = 0; nt < 4; ++nt)
            acc[mt][nt] = __builtin_amdgcn_mfma_f32_16x16x32_bf16(
                af[mt], bf[nt], acc[mt][nt], 0, 0, 0);
      }
      __syncthreads();
    }

    // ---- fold this d-plane into fin: fin += w[row,dd] * acc
#pragma unroll
    for (int mt = 0; mt < 4; ++mt) {
      const int rowb = m0 + wr * 64 + mt * 16 + quad * 4;
#pragma unroll
      for (int r = 0; r < 4; ++r) {
        const float ws_ = w[(size_t)(rowb + r) * D_ + dd];
#pragma unroll
        for (int nt = 0; nt < 4; ++nt) fin[mt][nt][r] += ws_ * acc[mt][nt][r];
      }
    }
  }

  // ---- epilogue: add bias term sum_d w[b,d]*biases[d,o], plain stores
  float bcol[4][8];
#pragma unroll
  for (int nt = 0; nt < 4; ++nt) {
    const int col = n0 + wc * 64 + nt * 16 + l16;
#pragma unroll
    for (int dd = 0; dd < 8; ++dd) bcol[nt][dd] = biases[dd * OUT_ + col];
  }
#pragma unroll
  for (int mt = 0; mt < 4; ++mt) {
#pragma unroll
    for (int r = 0; r < 4; ++r) {
      const int grow = m0 + wr * 64 + mt * 16 + quad * 4 + r;
      const v4f* wp = (const v4f*)(w + (size_t)grow * D_);
      const v4f wa = wp[0], wb = wp[1];
#pragma unroll
      for (int nt = 0; nt < 4; ++nt) {
        const int col = n0 + wc * 64 + nt * 16 + l16;
        const float bias = wa[0] * bcol[nt][0] + wa[1] * bcol[nt][1] +
                           wa[2] * bcol[nt][2] + wa[3] * bcol[nt][3] +
                           wb[0] * bcol[nt][4] + wb[1] * bcol[nt][5] +
                           wb[2] * bcol[nt][6] + wb[3] * bcol[nt][7];
        out[(size_t)grow * OUT_ + col] = fin[mt][nt][r] + bias;
      }
    }
  }
}

extern "C" void kernel_launch(void* const* d_in, const int* in_sizes, int n_in,
                              void* d_out, int out_size, void* d_ws, size_t ws_size,
                              hipStream_t stream) {
  const float* input   = (const float*)d_in[0];
  const float* w       = (const float*)d_in[1];
  const float* weights = (const float*)d_in[2];
  const float* biases  = (const float*)d_in[3];
  float* out = (float*)d_out;

  u16* inBf = (u16*)d_ws;                               // 16 MB
  u16* wtBf = inBf + (size_t)B_ * IN_;                  // 16 MB

  const int totalF4 = (B_ * IN_ + D_ * OUT_ * IN_) / 4;
  convert_both<<<dim3(totalF4 / 256), 256, 0, stream>>>(input, weights, inBf, wtBf);
  gemm_perd<<<dim3(512), 256, 0, stream>>>(inBf, wtBf, w, biases, out);
}

// Round 2
// 273.557 us; speedup vs baseline: 1.3241x; 1.3241x over previous
//
#include <hip/hip_runtime.h>
#include <stdint.h>

typedef unsigned short u16;
typedef float v4f __attribute__((ext_vector_type(4)));
typedef short v8s __attribute__((ext_vector_type(8)));

#define B_   8192
#define IN_  1024
#define OUT_ 1024
#define D_   8

#define BM 128
#define BN 128
#define BK 64             // K-tile per barrier pair (32 MFMAs amortize the drain)

// v_cvt_pk_bf16_f32: two f32 -> packed 2x bf16 (RTNE), single VALU op.
__device__ __forceinline__ uint32_t cvtpk(float lo, float hi) {
  uint32_t r;
  asm("v_cvt_pk_bf16_f32 %0, %1, %2" : "=v"(r) : "v"(lo), "v"(hi));
  return r;
}

// ---- prep: bf16 conversion of weights only (64 MB read + 16 MB write) ------
// input stays f32 and is scaled+converted on the fly inside the GEMM staging,
// so the 128 MB A' materialization (106 us in R0) disappears entirely.
__global__ __launch_bounds__(256) void convert_w(
    const float* __restrict__ weights, u16* __restrict__ wtBf) {
  const int i8 = blockIdx.x * 256 + threadIdx.x;   // 8 floats per thread
  const float4* src = (const float4*)weights + (size_t)i8 * 2;
  float4 a = src[0], b = src[1];
  uint4 o;
  o.x = cvtpk(a.x, a.y); o.y = cvtpk(a.z, a.w);
  o.z = cvtpk(b.x, b.y); o.w = cvtpk(b.z, b.w);
  ((uint4*)wtBf)[i8] = o;                          // 16B store
}

__device__ __forceinline__ void gload_lds16(const u16* g, u16* l) {
  typedef __attribute__((address_space(1))) void gvoid;
  typedef __attribute__((address_space(3))) void lvoid;
  __builtin_amdgcn_global_load_lds((gvoid*)g, (lvoid*)l, 16, 0, 0);
}

// ---- fused GEMM ------------------------------------------------------------
// Structure = proven R0 kernel (144 us, MfmaUtil 41%): 512 blocks (2/CU),
// XCD swizzle, BK=64 (32 MFMAs per barrier pair), XOR-swizzled LDS, ONE
// accumulator bank (out = acc + bias).
// Difference vs R0: the A operand is not the pre-materialized A' but raw f32
// input, scaled by w[row,dd] during staging (reg path: global f32 load ->
// v_mul -> v_cvt_pk_bf16_f32 -> ds_write_b128 at the SAME swizzled LDS
// address the old global_load_lds produced). B keeps global_load_lds.
// R1 lesson: the scale must happen pre-MFMA so only one accumulator bank
// exists (fin+acc=128 accum regs killed occupancy 21.6%->11.6%).
__global__ __launch_bounds__(256) void gemm_fused(
    const float* __restrict__ Ain,    // [B_][IN_] f32 input (unscaled)
    const u16* __restrict__ Wt,       // [D_][OUT_][IN_] bf16
    const float* __restrict__ w,      // [B_][D_]
    const float* __restrict__ biases, // [D_][OUT_]
    float* __restrict__ out) {        // [B_][OUT_]
  __shared__ __align__(16) u16 As[BM * BK];   // 16 KB
  __shared__ __align__(16) u16 Bs[BN * BK];   // 16 KB

  const int id   = blockIdx.x;                // 512 blocks
  const int xcd  = id & 7;
  const int slot = id >> 3;                   // 0..63
  const int by   = xcd + ((slot & 7) << 3);   // 0..63, 8 per XCD
  const int bx   = slot >> 3;                 // 0..7

  const int tid  = threadIdx.x;
  const int wid  = tid >> 6;
  const int lane = tid & 63;
  const int wr   = wid >> 1, wc = wid & 1;
  const int quad = lane >> 4, l16 = lane & 15;
  const int m0   = by * BM;
  const int n0   = bx * BN;

  // ---- staging geometry: 1024 chunks of 8 u16 per tile; thread -> 4 chunks
  // chunk c = wid*256 + j*64 + lane; row = c>>3 = wid*32 + j*8 + (lane>>3)
  // LDS chunk (lane&7) of row holds global column-chunk swz = (lane&7)^(row&7)
  const int swz  = (lane & 7) ^ ((lane >> 3) & 7);
  const int rowS = wid * 32 + (lane >> 3);    // + j*8
  const float* aBase[4];
  const u16*   bBase[4];
  uint32_t*    lA[4];
  u16*         lB[4];
#pragma unroll
  for (int j = 0; j < 4; ++j) {
    const int row = rowS + j * 8;
    aBase[j] = Ain + (size_t)(m0 + row) * IN_ + swz * 8;
    bBase[j] = Wt  + (size_t)(n0 + row) * IN_ + swz * 8;
    const int c = wid * 256 + j * 64 + lane;
    lA[j] = (uint32_t*)(As + c * 8);
    lB[j] = Bs + c * 8;
  }

  // ---- fragment LDS offsets (u16 index), de-swizzled
  const int aRow = wr * 64 + l16;
  const int bRow = wc * 64 + l16;
  const int e    = l16 & 7;
  int aC[2];
#pragma unroll
  for (int h = 0; h < 2; ++h) aC[h] = ((quad + 4 * h) ^ e) * 8;

  const v4f vzero = {0.f, 0.f, 0.f, 0.f};
  v4f acc[4][4];
#pragma unroll
  for (int mt = 0; mt < 4; ++mt)
#pragma unroll
    for (int nt = 0; nt < 4; ++nt) acc[mt][nt] = vzero;

  for (int dd = 0; dd < D_; ++dd) {
    const size_t bOffG = (size_t)dd * OUT_ * IN_;   // weights[dd] plane
    // per-d scale for the 4 rows this thread stages
    float ws[4];
#pragma unroll
    for (int j = 0; j < 4; ++j)
      ws[j] = w[(size_t)(m0 + rowS + j * 8) * D_ + dd];

    for (int it = 0; it < IN_ / BK; ++it) {         // 16 iters
      const int i0 = it * BK;
      // A: f32 loads first (latency head start)
      float4 a0[4], a1[4];
#pragma unroll
      for (int j = 0; j < 4; ++j) {
        const float4* ap = (const float4*)(aBase[j] + i0);
        a0[j] = ap[0];
        a1[j] = ap[1];
      }
      // B: async global->LDS
#pragma unroll
      for (int j = 0; j < 4; ++j) gload_lds16(bBase[j] + bOffG + i0, lB[j]);
      // A: scale, pack to bf16, ds_write_b128 into swizzled slot
#pragma unroll
      for (int j = 0; j < 4; ++j) {
        const float s = ws[j];
        uint4 pk;
        pk.x = cvtpk(a0[j].x * s, a0[j].y * s);
        pk.y = cvtpk(a0[j].z * s, a0[j].w * s);
        pk.z = cvtpk(a1[j].x * s, a1[j].y * s);
        pk.w = cvtpk(a1[j].z * s, a1[j].w * s);
        *(uint4*)lA[j] = pk;
      }
      __builtin_amdgcn_s_waitcnt(0);
      __syncthreads();

#pragma unroll
      for (int h = 0; h < 2; ++h) {
        v8s af[4], bf[4];
#pragma unroll
        for (int mt = 0; mt < 4; ++mt)
          af[mt] = *(const v8s*)(As + (aRow + mt * 16) * BK + aC[h]);
#pragma unroll
        for (int nt = 0; nt < 4; ++nt)
          bf[nt] = *(const v8s*)(Bs + (bRow + nt * 16) * BK + aC[h]);
#pragma unroll
        for (int mt = 0; mt < 4; ++mt)
#pragma unroll
          for (int nt = 0; nt < 4; ++nt)
            acc[mt][nt] = __builtin_amdgcn_mfma_f32_16x16x32_bf16(
                af[mt], bf[nt], acc[mt][nt], 0, 0, 0);
      }
      __syncthreads();
    }
  }

  // ---- epilogue: add bias term sum_d w[b,d]*biases[d,o], plain stores
  float bcol[4][8];
#pragma unroll
  for (int nt = 0; nt < 4; ++nt) {
    const int col = n0 + wc * 64 + nt * 16 + l16;
#pragma unroll
    for (int dd = 0; dd < 8; ++dd) bcol[nt][dd] = biases[dd * OUT_ + col];
  }
#pragma unroll
  for (int mt = 0; mt < 4; ++mt) {
#pragma unroll
    for (int r = 0; r < 4; ++r) {
      const int grow = m0 + wr * 64 + mt * 16 + quad * 4 + r;
      const v4f* wp = (const v4f*)(w + (size_t)grow * D_);
      const v4f wa = wp[0], wb = wp[1];
#pragma unroll
      for (int nt = 0; nt < 4; ++nt) {
        const int col = n0 + wc * 64 + nt * 16 + l16;
        const float bias = wa[0] * bcol[nt][0] + wa[1] * bcol[nt][1] +
                           wa[2] * bcol[nt][2] + wa[3] * bcol[nt][3] +
                           wb[0] * bcol[nt][4] + wb[1] * bcol[nt][5] +
                           wb[2] * bcol[nt][6] + wb[3] * bcol[nt][7];
        out[(size_t)grow * OUT_ + col] = acc[mt][nt][r] + bias;
      }
    }
  }
}

extern "C" void kernel_launch(void* const* d_in, const int* in_sizes, int n_in,
                              void* d_out, int out_size, void* d_ws, size_t ws_size,
                              hipStream_t stream) {
  const float* input   = (const float*)d_in[0];
  const float* w       = (const float*)d_in[1];
  const float* weights = (const float*)d_in[2];
  const float* biases  = (const float*)d_in[3];
  float* out = (float*)d_out;

  u16* wtBf = (u16*)d_ws;                               // 16 MB

  const int nThreads = (D_ * OUT_ * IN_) / 8;           // 8 floats/thread
  convert_w<<<dim3(nThreads / 256), 256, 0, stream>>>(weights, wtBf);
  gemm_fused<<<dim3(512), 256, 0, stream>>>(input, wtBf, w, biases, out);
}

// Round 3
// 233.685 us; speedup vs baseline: 1.5500x; 1.1706x over previous
//
#include <hip/hip_runtime.h>
#include <stdint.h>

typedef unsigned short u16;
typedef float v4f __attribute__((ext_vector_type(4)));
typedef short v8s __attribute__((ext_vector_type(8)));

#define B_   8192
#define IN_  1024
#define OUT_ 1024
#define D_   8

#define BM 128
#define BN 128
#define BK 64             // K-tile per phase: 32 MFMAs

__device__ __forceinline__ u16 f2bf(float f) {
  uint32_t u = __float_as_uint(f);
  u += 0x7fffu + ((u >> 16) & 1u);   // RTNE (inputs finite)
  return (u16)(u >> 16);
}

// v_cvt_pk_bf16_f32: two f32 -> packed 2x bf16 (RTNE), single VALU op.
__device__ __forceinline__ uint32_t cvtpk(float lo, float hi) {
  uint32_t r;
  asm("v_cvt_pk_bf16_f32 %0, %1, %2" : "=v"(r) : "v"(lo), "v"(hi));
  return r;
}

// ---- prep: weights f32 -> bf16 (32 MB read + 16 MB write) ------------------
// scalar f2bf path (m240: inline-asm cvt_pk hurts in standalone converts).
__global__ __launch_bounds__(256) void convert_w(
    const float* __restrict__ weights, u16* __restrict__ wtBf) {
  const int i4 = blockIdx.x * 256 + threadIdx.x;
  float4 v = ((const float4*)weights)[i4];
  ushort4 o;
  o.x = f2bf(v.x); o.y = f2bf(v.y); o.z = f2bf(v.z); o.w = f2bf(v.w);
  ((ushort4*)wtBf)[i4] = o;
}

__device__ __forceinline__ void gload_lds16(const u16* g, u16* l) {
  typedef __attribute__((address_space(1))) void gvoid;
  typedef __attribute__((address_space(3))) void lvoid;
  __builtin_amdgcn_global_load_lds((gvoid*)g, (lvoid*)l, 16, 0, 0);
}

// ---- fused GEMM, double-buffered 2-phase pipeline --------------------------
// R2 lessons fixed here:
//   (a) d is INNERMOST: the f32 A-chunk is loaded to regs once per it and
//       re-scaled from regs for each of 8 d's -> A global traffic /8
//       (R2 FETCH 197 MB from 8x f32 A re-read).
//   (b) LDS double-buffered (As/Bs x2, 64 KB): stage t+1 (B gload_lds + A
//       scale/cvt/ds_write) overlaps the 32-MFMA compute of t; ONE barrier
//       per phase. R2's single-buffer put A-load latency + scale VALU
//       between the barriers (MfmaUtil 41->28).
// dd-loop fully unrolled: cur/nxt, staged-d, w-select all compile-time
// (static LDS indices -> no scratch, provable no-alias; rule #20).
__global__ __launch_bounds__(256, 2) void gemm_fused(
    const float* __restrict__ Ain,    // [B_][IN_] f32 input (unscaled)
    const u16* __restrict__ Wt,       // [D_][OUT_][IN_] bf16
    const float* __restrict__ w,      // [B_][D_]
    const float* __restrict__ biases, // [D_][OUT_]
    float* __restrict__ out) {        // [B_][OUT_]
  __shared__ __align__(16) u16 As[2][BM * BK];   // 32 KB
  __shared__ __align__(16) u16 Bs[2][BN * BK];   // 32 KB

  const int id   = blockIdx.x;                // 512 blocks (2/CU)
  const int xcd  = id & 7;
  const int slot = id >> 3;                   // 0..63
  const int by   = xcd + ((slot & 7) << 3);   // 8 per XCD
  const int bx   = slot >> 3;                 // 0..7

  const int tid  = threadIdx.x;
  const int wid  = tid >> 6;
  const int lane = tid & 63;
  const int wr   = wid >> 1, wc = wid & 1;
  const int quad = lane >> 4, l16 = lane & 15;
  const int m0   = by * BM;
  const int n0   = bx * BN;

  // staging geometry (proven R2): chunk c = wid*256+j*64+lane;
  // row = wid*32+j*8+(lane>>3); LDS chunk (lane&7) holds global chunk
  // swz = (lane&7)^(row&7); j-invariant.
  const int swz  = (lane & 7) ^ ((lane >> 3) & 7);
  const int rowS = wid * 32 + (lane >> 3);    // + j*8
  const float* aBase[4];
  const u16*   bBase[4];
  int cOff[4];                                // u16 offset within one buffer
#pragma unroll
  for (int j = 0; j < 4; ++j) {
    const int row = rowS + j * 8;
    aBase[j] = Ain + (size_t)(m0 + row) * IN_ + swz * 8;
    bBase[j] = Wt  + (size_t)(n0 + row) * IN_ + swz * 8;
    cOff[j]  = (wid * 256 + j * 64 + lane) * 8;
  }

  // per-row w[0..7] preloaded once (static-index select after unroll)
  float4 wA[4], wB[4];
#pragma unroll
  for (int j = 0; j < 4; ++j) {
    const float* wp = w + (size_t)(m0 + rowS + j * 8) * D_;
    wA[j] = ((const float4*)wp)[0];
    wB[j] = ((const float4*)wp)[1];
  }

  // fragment LDS offsets (u16 index), de-swizzled
  const int aRow = wr * 64 + l16;
  const int bRow = wc * 64 + l16;
  const int e    = l16 & 7;
  int aC[2];
#pragma unroll
  for (int h = 0; h < 2; ++h) aC[h] = ((quad + 4 * h) ^ e) * 8;

  const v4f vzero = {0.f, 0.f, 0.f, 0.f};
  v4f acc[4][4];
#pragma unroll
  for (int mt = 0; mt < 4; ++mt)
#pragma unroll
    for (int nt = 0; nt < 4; ++nt) acc[mt][nt] = vzero;

  float4 a0[4], a1[4];   // f32 A-chunk for the it currently being staged

  // ---- prologue: stage (it=0, dd=0) into buffer 0
#pragma unroll
  for (int j = 0; j < 4; ++j) {
    const float4* ap = (const float4*)aBase[j];
    a0[j] = ap[0]; a1[j] = ap[1];
  }
#pragma unroll
  for (int j = 0; j < 4; ++j) gload_lds16(bBase[j], &Bs[0][cOff[j]]);
#pragma unroll
  for (int j = 0; j < 4; ++j) {
    const float s = wA[j].x;   // dd = 0
    uint4 pk;
    pk.x = cvtpk(a0[j].x * s, a0[j].y * s);
    pk.y = cvtpk(a0[j].z * s, a0[j].w * s);
    pk.z = cvtpk(a1[j].x * s, a1[j].y * s);
    pk.w = cvtpk(a1[j].z * s, a1[j].w * s);
    *(uint4*)(&As[0][cOff[j]]) = pk;
  }
  __builtin_amdgcn_s_waitcnt(0);
  __syncthreads();

  // ---- main: 16 it x 8 dd phases; phase t computes [cur], stages t+1 -> [nxt]
  for (int it = 0; it < IN_ / BK; ++it) {
#pragma unroll
    for (int dd = 0; dd < D_; ++dd) {
      const int cur = dd & 1;            // t = it*8+dd; it*8 even
      const int nxt = cur ^ 1;
      const int sdd = (dd + 1) & 7;      // staged dd (compile-time)
      const bool last = (it == IN_ / BK - 1) && (dd == D_ - 1);

      // -- issue staging loads for t+1 (before compute, latency under MFMA)
      if (!last) {
        const int sit = (dd == D_ - 1) ? it + 1 : it;
        if (dd == D_ - 1) {              // new it: reload A f32 chunk
#pragma unroll
          for (int j = 0; j < 4; ++j) {
            const float4* ap = (const float4*)(aBase[j] + sit * BK);
            a0[j] = ap[0]; a1[j] = ap[1];
          }
        }
#pragma unroll
        for (int j = 0; j < 4; ++j)
          gload_lds16(bBase[j] + (size_t)sdd * (OUT_ * IN_) + sit * BK,
                      &Bs[nxt][cOff[j]]);
      }

      // -- compute on [cur]
#pragma unroll
      for (int h = 0; h < 2; ++h) {
        v8s af[4], bf[4];
#pragma unroll
        for (int mt = 0; mt < 4; ++mt)
          af[mt] = *(const v8s*)(&As[cur][(aRow + mt * 16) * BK + aC[h]]);
#pragma unroll
        for (int nt = 0; nt < 4; ++nt)
          bf[nt] = *(const v8s*)(&Bs[cur][(bRow + nt * 16) * BK + aC[h]]);
#pragma unroll
        for (int mt = 0; mt < 4; ++mt)
#pragma unroll
          for (int nt = 0; nt < 4; ++nt)
            acc[mt][nt] = __builtin_amdgcn_mfma_f32_16x16x32_bf16(
                af[mt], bf[nt], acc[mt][nt], 0, 0, 0);
      }

      // -- finish staging: scale A from regs, pack, ds_write into [nxt]
      if (!last) {
#pragma unroll
        for (int j = 0; j < 4; ++j) {
          const float s = (sdd < 4) ? wA[j][sdd] : wB[j][sdd - 4];
          uint4 pk;
          pk.x = cvtpk(a0[j].x * s, a0[j].y * s);
          pk.y = cvtpk(a0[j].z * s, a0[j].w * s);
          pk.z = cvtpk(a1[j].x * s, a1[j].y * s);
          pk.w = cvtpk(a1[j].z * s, a1[j].w * s);
          *(uint4*)(&As[nxt][cOff[j]]) = pk;
        }
      }
      __builtin_amdgcn_s_waitcnt(0);     // drain B gload_lds + A ds_write
      __syncthreads();                   // ONE barrier per phase
    }
  }

  // ---- epilogue: add bias term sum_d w[b,d]*biases[d,o], plain stores
  float bcol[4][8];
#pragma unroll
  for (int nt = 0; nt < 4; ++nt) {
    const int col = n0 + wc * 64 + nt * 16 + l16;
#pragma unroll
    for (int dd = 0; dd < 8; ++dd) bcol[nt][dd] = biases[dd * OUT_ + col];
  }
#pragma unroll
  for (int mt = 0; mt < 4; ++mt) {
#pragma unroll
    for (int r = 0; r < 4; ++r) {
      const int grow = m0 + wr * 64 + mt * 16 + quad * 4 + r;
      const v4f* wp = (const v4f*)(w + (size_t)grow * D_);
      const v4f wa = wp[0], wb = wp[1];
#pragma unroll
      for (int nt = 0; nt < 4; ++nt) {
        const int col = n0 + wc * 64 + nt * 16 + l16;
        const float bias = wa[0] * bcol[nt][0] + wa[1] * bcol[nt][1] +
                           wa[2] * bcol[nt][2] + wa[3] * bcol[nt][3] +
                           wb[0] * bcol[nt][4] + wb[1] * bcol[nt][5] +
                           wb[2] * bcol[nt][6] + wb[3] * bcol[nt][7];
        out[(size_t)grow * OUT_ + col] = acc[mt][nt][r] + bias;
      }
    }
  }
}

extern "C" void kernel_launch(void* const* d_in, const int* in_sizes, int n_in,
                              void* d_out, int out_size, void* d_ws, size_t ws_size,
                              hipStream_t stream) {
  const float* input   = (const float*)d_in[0];
  const float* w       = (const float*)d_in[1];
  const float* weights = (const float*)d_in[2];
  const float* biases  = (const float*)d_in[3];
  float* out = (float*)d_out;

  u16* wtBf = (u16*)d_ws;                               // 16 MB

  const int nF4 = (D_ * OUT_ * IN_) / 4;                // one float4 / thread
  convert_w<<<dim3(nF4 / 256), 256, 0, stream>>>(weights, wtBf);
  gemm_fused<<<dim3(512), 256, 0, stream>>>(input, wtBf, w, biases, out);
}